// Round 15
// baseline (12986.481 us; speedup 1.0000x reference)
//
#include <hip/hip_runtime.h>
#include <stdint.h>
#include <stddef.h>

// LSTMQNetwork: B=64, T=4096, D=128, H=512, A=18
//
// R15 = R14 (10.56ms, passed) reorganized to 16-batch groups:
//  - 4 groups x 16 batch rows (was 8x8). Producers: 64 blocks (g=bid&3,
//    k=bid>>2); workers: 4 blocks (bid 64..67). 68 agents total (was 136)
//    -> half the LIC requestors/arbitration.
//  - every MFMA B row is now a live batch (R14 wasted rows 8..15 as zeros):
//    same 40 MFMAs/CU/step, 2x useful throughput, no n<8 guards.
//  - ring slot = 16 rows x 512 cols bf16 (16KB); wave-quarter poll = 16 rows
//    x 32 u64 cols: prow=l>>2, pcol=w*32+(l&3), 8 u64/lane at stride 4.
//  - workers consume the full 16-row A-operand; all kg rows store out.
//  - parity data-as-flag protocol, transposed-MFMA gate layout, colsum bias
//    correction, LDS dbuf staging, back-pressure, watchdog: all from R14.

#define B_   64
#define T_   4096
#define D_   128
#define H_   512
#define G4_  2048
#define A_   18
#define QOFF (2 * B_ * H_)
#define BIAS 1.5f

typedef float f32x4  __attribute__((ext_vector_type(4)));
typedef short bf16x8 __attribute__((ext_vector_type(8)));
typedef unsigned long long u64;
#define MFMA __builtin_amdgcn_mfma_f32_16x16x32_bf16

#define QD_IDX(g,w)  (((g) * 4 + (w)) * 16)   // worker progress, 1/64B line
#define CTL_DWORDS   1024
#define HS_OFF       65536                    // ring byte offset in ws
#define TLIM         400000000ull             // ~4 s at 100 MHz
#define SMASK        0x8000800080008000ull
#define SLOT_SH      8192                     // shorts per slot (16 x 512)

__device__ __forceinline__ short f2bf(float x) {
    union { float f; uint32_t u; } v; v.f = x;
    uint32_t r = (v.u + 0x7fffu + ((v.u >> 16) & 1u)) >> 16;  // RNE
    return (short)(uint16_t)r;
}
__device__ __forceinline__ float bf2f(short s) {
    union { uint32_t u; float f; } v; v.u = ((uint32_t)(uint16_t)s) << 16;
    return v.f;
}
__device__ __forceinline__ float sigm(float x) {
    return __builtin_amdgcn_rcpf(1.0f + __builtin_amdgcn_exp2f(-1.4426950408889634f * x));
}
__device__ __forceinline__ float tanh_(float x) {
    return 2.0f * __builtin_amdgcn_rcpf(1.0f + __builtin_amdgcn_exp2f(-2.8853900817779268f * x)) - 1.0f;
}

// zero ctl; stamp whole ring stale (0x8000 = -0.0 -> stale for gen 0)
__global__ void lstm_fill(unsigned* __restrict__ ctl, uint4* __restrict__ hs4,
                          int nchunks) {
    int idx = blockIdx.x * blockDim.x + threadIdx.x;
    int nt  = gridDim.x * blockDim.x;
    for (int i = idx; i < CTL_DWORDS; i += nt) ctl[i] = 0u;
    const uint4 v = {0x80008000u, 0x80008000u, 0x80008000u, 0x80008000u};
    for (int i = idx; i < nchunks; i += nt) hs4[i] = v;
}

// seed ring slot 0 with h_0 + 1.5 (generation 0 => positive sign)
__global__ void lstm_init0(const float* __restrict__ init_h,
                           short* __restrict__ hs, int R) {
    int idx = blockIdx.x * blockDim.x + threadIdx.x;
    int nt  = gridDim.x * blockDim.x;
    for (int e = idx; e < B_ * H_; e += nt) {
        int row = e >> 9, col = e & 511;
        int g = row >> 4, r16 = row & 15;
        hs[(size_t)g * R * SLOT_SH + (size_t)r16 * 512 + col] = f2bf(init_h[e] + BIAS);
    }
}

__global__ void __launch_bounds__(256, 1) lstm_main(
    const float* __restrict__ obses, const float* __restrict__ init_c,
    const float* __restrict__ Wi,    const float* __restrict__ Wh,
    const float* __restrict__ bvec,  const float* __restrict__ Wv,
    const float* __restrict__ bv,    float* __restrict__ out,
    unsigned* ctl, short* hs, int R, int lg2R)
{
    const int bid = blockIdx.x;
    const int w   = threadIdx.x >> 6;
    const int l   = threadIdx.x & 63;
    const int n   = l & 15;
    const int kg  = l >> 4;
    const int Rm  = R - 1;
    const unsigned long long t_start = __builtin_amdgcn_s_memrealtime();
    bool tmo = false;

    if (bid < 64) {
        // ---------------- recurrence producer (transposed MFMA) ----------------
        __shared__ u64 lds_h[2][16 * 132];   // dbuf: 16 rows x 128 u64, stride 132
        const int g = bid & 3;
        const int k = bid >> 2;              // 0..15
        short* hsg = hs + (size_t)g * R * SLOT_SH;

        const int cw  = k * 32 + w * 8;                 // wave's h-col base
        const int gc0 = (n & 3) * 512 + cw + (n >> 2);  // A-row n -> gate col (tile0)
        const int gc1 = gc0 + 4;                        // tile1

        // stationary weight A-frags + colsums
        bf16x8 whA0[16], whA1[16], wiA0[4], wiA1[4];
        float ws0 = 0.f, ws1 = 0.f;
#pragma unroll
        for (int ch = 0; ch < 16; ++ch) {
            bf16x8 v0, v1;
#pragma unroll
            for (int j = 0; j < 8; ++j) {
                const size_t kr = (size_t)(ch * 32 + kg * 8 + j) * G4_;
                short s0 = f2bf(Wh[kr + gc0]); v0[j] = s0; ws0 += bf2f(s0);
                short s1 = f2bf(Wh[kr + gc1]); v1[j] = s1; ws1 += bf2f(s1);
            }
            whA0[ch] = v0; whA1[ch] = v1;
        }
#pragma unroll
        for (int ch = 0; ch < 4; ++ch) {
            bf16x8 v0, v1;
#pragma unroll
            for (int j = 0; j < 8; ++j) {
                const size_t kr = (size_t)(ch * 32 + kg * 8 + j) * G4_;
                v0[j] = f2bf(Wi[kr + gc0]);
                v1[j] = f2bf(Wi[kr + gc1]);
            }
            wiA0[ch] = v0; wiA1[ch] = v1;
        }
        ws0 += __shfl_xor(ws0, 16); ws0 += __shfl_xor(ws0, 32);
        ws1 += __shfl_xor(ws1, 16); ws1 += __shfl_xor(ws1, 32);
        const float b0v = bvec[gc0], b1v = bvec[gc1];
        const float sP0 = b0v - BIAS * ws0, sM0 = b0v + BIAS * ws0;
        const float sP1 = b1v - BIAS * ws1, sM1 = b1v + BIAS * ws1;
        f32x4 sdP0, sdM0, sdP1, sdM1;
#pragma unroll
        for (int r = 0; r < 4; ++r) {
            sdP0[r] = __shfl(sP0, kg * 4 + r); sdM0[r] = __shfl(sM0, kg * 4 + r);
            sdP1[r] = __shfl(sP1, kg * 4 + r); sdM1[r] = __shfl(sM1, kg * 4 + r);
        }

        // c state: lane (kg, n) owns batch g*16+n, cols cw+kg / cw+4+kg
        float cst0 = init_c[(size_t)(g * 16 + n) * H_ + cw + kg];
        float cst1 = init_c[(size_t)(g * 16 + n) * H_ + cw + 4 + kg];
        float hl0 = 0.f, hl1 = 0.f;

        // obs double-buffer in registers (all 16 lanes live now)
        f32x4 oraw[8];
        {
            const float* src = obses + ((size_t)(g * 16 + n) * T_ + 0) * D_ + kg * 8;
#pragma unroll
            for (int ch = 0; ch < 4; ++ch) {
                oraw[2 * ch]     = *(const f32x4*)(src + ch * 32);
                oraw[2 * ch + 1] = *(const f32x4*)(src + ch * 32 + 4);
            }
        }

        // payload-quarter mapping: wave w covers u64 cols [w*32, w*32+32)
        // over 16 rows; lane: row l>>2, cols w*32 + (l&3) + 4j (j=0..7)
        const int prow = l >> 2;
        const int pcol = w * 32 + (l & 3);

        const int CHK  = R >> 2;
        const int CHKm = CHK - 1;

        for (int t = 0; t < T_ && !tmo; ++t) {
            // ---- back-pressure vs qs workers (rare) ----
            if ((t & CHKm) == 0) {
                const int need = t + CHK + 4 - R;
                if (need > 0) {
                    int spin = 0; bool ok;
                    do {
                        int p = 0x7fffffff;
                        if (l < 4)
                            p = 1 + l + 4 * (int)__hip_atomic_load(ctl + QD_IDX(g, l),
                                    __ATOMIC_RELAXED, __HIP_MEMORY_SCOPE_AGENT);
                        ok = (__all(p >= need) != 0);
                        if (!ok && ((++spin) & 63) == 0 &&
                            (__builtin_amdgcn_s_memrealtime() - t_start) > TLIM) { tmo = true; break; }
                    } while (!ok);
                    if (tmo) break;
                }
            }

            const bool  pos = (((t >> lg2R) & 1) == 0);
            const float bh1 = (((t + 1) >> lg2R) & 1) ? -BIAS : BIAS;

            // ---- x-projection from prefetched obs; prefetch next ----
            bf16x8 obsF[4];
#pragma unroll
            for (int ch = 0; ch < 4; ++ch) {
                bf16x8 v;
#pragma unroll
                for (int j = 0; j < 4; ++j) {
                    v[j]     = f2bf(oraw[2 * ch][j]);
                    v[4 + j] = f2bf(oraw[2 * ch + 1][j]);
                }
                obsF[ch] = v;
            }
            if (t + 1 < T_) {
                const float* src = obses + ((size_t)(g * 16 + n) * T_ + (t + 1)) * D_ + kg * 8;
#pragma unroll
                for (int ch = 0; ch < 4; ++ch) {
                    oraw[2 * ch]     = *(const f32x4*)(src + ch * 32);
                    oraw[2 * ch + 1] = *(const f32x4*)(src + ch * 32 + 4);
                }
            }

            // transposed xproj: A = Wi frags, B = obs frags
            f32x4 aE0 = pos ? sdP0 : sdM0;
            f32x4 aE1 = pos ? sdP1 : sdM1;
            f32x4 aO0 = {0.f, 0.f, 0.f, 0.f}, aO1 = {0.f, 0.f, 0.f, 0.f};
            aE0 = MFMA(wiA0[0], obsF[0], aE0, 0, 0, 0);
            aO0 = MFMA(wiA0[1], obsF[1], aO0, 0, 0, 0);
            aE0 = MFMA(wiA0[2], obsF[2], aE0, 0, 0, 0);
            aO0 = MFMA(wiA0[3], obsF[3], aO0, 0, 0, 0);
            aE1 = MFMA(wiA1[0], obsF[0], aE1, 0, 0, 0);
            aO1 = MFMA(wiA1[1], obsF[1], aO1, 0, 0, 0);
            aE1 = MFMA(wiA1[2], obsF[2], aE1, 0, 0, 0);
            aO1 = MFMA(wiA1[3], obsF[3], aO1, 0, 0, 0);

            // ---- parity-poll OWN quarter (8 u64/lane) ----
            {
                const u64* hp = (const u64*)(hsg + (size_t)(t & Rm) * SLOT_SH)
                                + prow * 128 + pcol;
                const u64 e64 = pos ? 0ull : SMASK;
                u64 q[8];
                int spin = 0;
                for (;;) {
#pragma unroll
                    for (int j = 0; j < 8; ++j)
                        q[j] = __hip_atomic_load(hp + 4 * j, __ATOMIC_RELAXED, __HIP_MEMORY_SCOPE_AGENT);
                    u64 bad = 0;
#pragma unroll
                    for (int j = 0; j < 8; ++j) bad |= (q[j] ^ e64);
                    if (__all((int)((bad & SMASK) == 0ull))) break;
                    if (((++spin) & 255) == 0 &&
                        (__builtin_amdgcn_s_memrealtime() - t_start) > TLIM) { tmo = true; break; }
                }
                if (tmo) break;
                u64* dst = &lds_h[t & 1][prow * 132 + pcol];
#pragma unroll
                for (int j = 0; j < 8; ++j) dst[4 * j] = q[j];
            }
            __syncthreads();

            // ---- recurrent MFMAs: A = Wh frags, B = h frags from LDS ----
            const u64* lb = &lds_h[t & 1][n * 132 + kg * 2];
#pragma unroll
            for (int ch = 0; ch < 16; ++ch) {
                union { u64 q[2]; bf16x8 v; } u;
                u.q[0] = lb[ch * 8]; u.q[1] = lb[ch * 8 + 1];
                if (ch & 1) { aO0 = MFMA(whA0[ch], u.v, aO0, 0, 0, 0);
                              aO1 = MFMA(whA1[ch], u.v, aO1, 0, 0, 0); }
                else        { aE0 = MFMA(whA0[ch], u.v, aE0, 0, 0, 0);
                              aE1 = MFMA(whA1[ch], u.v, aE1, 0, 0, 0); }
            }

            // ---- gates in-lane ----
            f32x4 x0 = aE0 + aO0, x1 = aE1 + aO1;
            float nc0 = sigm(x0[1]) * cst0 + sigm(x0[0]) * tanh_(x0[2]);
            float nh0 = sigm(x0[3]) * tanh_(nc0);
            float nc1 = sigm(x1[1]) * cst1 + sigm(x1[0]) * tanh_(x1[2]);
            float nh1 = sigm(x1[3]) * tanh_(nc1);
            cst0 = nc0; cst1 = nc1; hl0 = nh0; hl1 = nh1;

            // ---- pack row segment (cols cw..cw+7) and publish (all n) ----
            {
                const int slw = (t + 1) & Rm;
                unsigned v = (unsigned)(unsigned short)f2bf(nh0 + bh1) |
                             ((unsigned)(unsigned short)f2bf(nh1 + bh1) << 16);
                unsigned p  = (unsigned)__shfl_xor((int)v, 16);   // kg^1
                unsigned dwA = (v & 0xffffu) | (p << 16);         // cols kg,kg^1 (t0)
                unsigned dwB = (v >> 16) | (p & 0xffff0000u);     // cols kg,kg^1 (t1)
                unsigned qA = (unsigned)__shfl_xor((int)dwA, 32); // kg^2 pair
                unsigned qB = (unsigned)__shfl_xor((int)dwB, 32);
                u64 lo = (u64)dwA | ((u64)qA << 32);  // cols cw+0..3
                u64 hi = (u64)dwB | ((u64)qB << 32);  // cols cw+4..7
                if (kg == 0) {
                    u64* dst = (u64*)(hsg + (size_t)slw * SLOT_SH + (size_t)n * 512 + cw);
                    __hip_atomic_store(dst,     lo, __ATOMIC_RELAXED, __HIP_MEMORY_SCOPE_AGENT);
                    __hip_atomic_store(dst + 1, hi, __ATOMIC_RELAXED, __HIP_MEMORY_SCOPE_AGENT);
                }
            }
            // fire-and-forget — parity in the data is the flag
        }

        // ---- final c, h (fp32 from registers) ----
        if (!tmo) {
            const size_t brow = (size_t)(g * 16 + n);
            out[brow * H_ + cw + kg]     = cst0;
            out[brow * H_ + cw + 4 + kg] = cst1;
            out[(size_t)B_ * H_ + brow * H_ + cw + kg]     = hl0;
            out[(size_t)B_ * H_ + brow * H_ + cw + 4 + kg] = hl1;
        }
    } else if (bid < 68) {
        // ---------------- qs worker (1 per group) ----------------
        const int g = bid - 64;
        short* hsg = hs + (size_t)g * R * SLOT_SH;

        bf16x8 wvF[2][16]; float wvsum[2] = {0.f, 0.f}; float bvv[2];
#pragma unroll
        for (int c = 0; c < 2; ++c) {
            const int a  = c * 16 + n;
            const bool va = (a < A_);
#pragma unroll
            for (int ch = 0; ch < 16; ++ch) {
                bf16x8 v;
#pragma unroll
                for (int j = 0; j < 8; ++j) {
                    short sbf = va ? f2bf(Wv[(size_t)(ch * 32 + kg * 8 + j) * A_ + a]) : (short)0;
                    v[j] = sbf; wvsum[c] += bf2f(sbf);
                }
                wvF[c][ch] = v;
            }
            bvv[c] = va ? bv[a] : 0.f;
        }
#pragma unroll
        for (int c = 0; c < 2; ++c) {
            wvsum[c] += __shfl_xor(wvsum[c], 16);
            wvsum[c] += __shfl_xor(wvsum[c], 32);
        }

        u64 hq[32];

        unsigned cnt = 0;
        for (int s = 1 + w; s <= T_ && !tmo; s += 4) {
            const float bh = ((s >> lg2R) & 1) ? -BIAS : BIAS;
            const u64 e64 = (bh > 0.f) ? 0ull : SMASK;
            {
                // lane (kg, n): row n, u64 cols kg*2 + ch*8 (+1)
                const u64* hp = (const u64*)(hsg + (size_t)(s & Rm) * SLOT_SH)
                                + n * 128 + kg * 2;
                int spin = 0; bool fresh;
                do {
                    u64 bad = 0;
#pragma unroll
                    for (int ch = 0; ch < 16; ++ch) {
                        hq[2 * ch]     = __hip_atomic_load(hp + ch * 8,     __ATOMIC_RELAXED, __HIP_MEMORY_SCOPE_AGENT);
                        hq[2 * ch + 1] = __hip_atomic_load(hp + ch * 8 + 1, __ATOMIC_RELAXED, __HIP_MEMORY_SCOPE_AGENT);
                    }
#pragma unroll
                    for (int i = 0; i < 32; ++i) bad |= (hq[i] ^ e64);
                    fresh = ((bad & SMASK) == 0ull);
                    if (__all(fresh)) break;
                    __builtin_amdgcn_s_sleep(2);
                    if (((++spin) & 255) == 0 &&
                        (__builtin_amdgcn_s_memrealtime() - t_start) > TLIM) { tmo = true; break; }
                } while (true);
                if (tmo) break;
            }

            // payload in regs -> progress immediately
            ++cnt;
            asm volatile("" ::: "memory");
            if (l == 0)
                __hip_atomic_store(ctl + QD_IDX(g, w), cnt,
                                   __ATOMIC_RELAXED, __HIP_MEMORY_SCOPE_AGENT);

            const float q0s = bvv[0] - bh * wvsum[0];
            const float q1s = bvv[1] - bh * wvsum[1];
            f32x4 q0 = {q0s, q0s, q0s, q0s};
            f32x4 q1 = {q1s, q1s, q1s, q1s};
#pragma unroll
            for (int ch = 0; ch < 16; ++ch) {
                union { u64 q[2]; bf16x8 v; } u;
                u.q[0] = hq[2 * ch]; u.q[1] = hq[2 * ch + 1];
                q0 = MFMA(u.v, wvF[0][ch], q0, 0, 0, 0);
                q1 = MFMA(u.v, wvF[1][ch], q1, 0, 0, 0);
            }

            const int tau = s - 1;
#pragma unroll
            for (int c = 0; c < 2; ++c) {
                const int a = c * 16 + n;
                if (a < A_) {
                    const f32x4 q = c ? q1 : q0;
#pragma unroll
                    for (int r = 0; r < 4; ++r)
                        out[QOFF + ((size_t)(g * 16 + kg * 4 + r) * T_ + tau) * A_ + a] = q[r];
                }
            }
        }
    }
}

extern "C" void kernel_launch(void* const* d_in, const int* in_sizes, int n_in,
                              void* d_out, int out_size, void* d_ws, size_t ws_size,
                              hipStream_t stream) {
    const float* obses  = (const float*)d_in[0];
    const float* init_c = (const float*)d_in[1];
    const float* init_h = (const float*)d_in[2];
    const float* Wi     = (const float*)d_in[3];
    const float* Wh     = (const float*)d_in[4];
    const float* b      = (const float*)d_in[5];
    const float* Wv     = (const float*)d_in[6];
    const float* bv     = (const float*)d_in[7];
    float* out = (float*)d_out;

    unsigned* ctl = (unsigned*)d_ws;
    short*    hs  = (short*)((char*)d_ws + HS_OFF);

    // ring: 4 groups * R slots * 16KB
    int R = 32;
    while (R > 8 && (size_t)HS_OFF + 4ull * R * 16384ull > ws_size) R >>= 1;
    int lg2R = 31 - __builtin_clz((unsigned)R);

    int nchunks = R * 4096;  // 4 groups * R slots * 16384 B / 16 B

    hipLaunchKernelGGL(lstm_fill,  dim3(256), dim3(256), 0, stream, ctl, (uint4*)hs, nchunks);
    hipLaunchKernelGGL(lstm_init0, dim3(64),  dim3(256), 0, stream, init_h, hs, R);
    hipLaunchKernelGGL(lstm_main,  dim3(68),  dim3(256), 0, stream,
                       obses, init_c, Wi, Wh, b, Wv, bv, out, ctl, hs, R, lg2R);
}

// Round 17
// 10579.819 us; speedup vs baseline: 1.2275x; 1.2275x over previous
//
#include <hip/hip_runtime.h>
#include <stdint.h>
#include <stddef.h>

// LSTMQNetwork: B=64, T=4096, D=128, H=512, A=18
//
// R18 = R14 VERBATIM (10.56ms, passed — best verified).
//  - 8 groups (bid&7) x 16 CUs (bid>>3); CU owns 32 h-cols, 4 waves x 2
//    col-tiles; transposed MFMA (A=weights, B=h/obs) -> gates land in-lane.
//  - parity data-as-flag: h' = h + s*1.5, s = ring-generation parity sign;
//    colsum bias correction folded into gate seeds (two variants).
//  - consumers parity-poll their OWN 2KB slot quarter (4 u64/lane, relaxed
//    agent atomics; the detecting read IS the payload) -> LDS dbuf -> MFMA.
//  - producers publish 2 u64/row-segment, fire-and-forget; no fences, no
//    sentinels, no syncthreads on the publish path.
//  - geometry experiments CLOSED: R15 (16-batch groups) regressed 23%
//    (poll coalescing + stragglers); R17 (8-wave blocks) deadlocked.
//    XCD-local fabric CLOSED (R6/R8/R9/R13).
//  - step time = ~2 die-level coherence legs (~2.2us) + compute (~0.4us);
//    4096 sequential steps -> ~10.5ms = measured. Latency floor of this
//    platform's cross-CU coherence path.

#define B_   64
#define T_   4096
#define D_   128
#define H_   512
#define G4_  2048
#define A_   18
#define QOFF (2 * B_ * H_)
#define BIAS 1.5f

typedef float f32x4  __attribute__((ext_vector_type(4)));
typedef short bf16x8 __attribute__((ext_vector_type(8)));
typedef unsigned long long u64;
#define MFMA __builtin_amdgcn_mfma_f32_16x16x32_bf16

#define QD_IDX(g,w)  (((g) * 4 + (w)) * 16)   // worker progress, 1/64B line
#define CTL_DWORDS   1024
#define HS_OFF       65536                    // ring byte offset in ws
#define TLIM         400000000ull             // ~4 s at 100 MHz
#define SMASK        0x8000800080008000ull

__device__ __forceinline__ short f2bf(float x) {
    union { float f; uint32_t u; } v; v.f = x;
    uint32_t r = (v.u + 0x7fffu + ((v.u >> 16) & 1u)) >> 16;  // RNE
    return (short)(uint16_t)r;
}
__device__ __forceinline__ float bf2f(short s) {
    union { uint32_t u; float f; } v; v.u = ((uint32_t)(uint16_t)s) << 16;
    return v.f;
}
__device__ __forceinline__ float sigm(float x) {
    return __builtin_amdgcn_rcpf(1.0f + __builtin_amdgcn_exp2f(-1.4426950408889634f * x));
}
__device__ __forceinline__ float tanh_(float x) {
    return 2.0f * __builtin_amdgcn_rcpf(1.0f + __builtin_amdgcn_exp2f(-2.8853900817779268f * x)) - 1.0f;
}

// zero ctl; stamp whole ring stale (0x8000 = -0.0 -> stale for gen 0)
__global__ void lstm_fill(unsigned* __restrict__ ctl, uint4* __restrict__ hs4,
                          int nchunks) {
    int idx = blockIdx.x * blockDim.x + threadIdx.x;
    int nt  = gridDim.x * blockDim.x;
    for (int i = idx; i < CTL_DWORDS; i += nt) ctl[i] = 0u;
    const uint4 v = {0x80008000u, 0x80008000u, 0x80008000u, 0x80008000u};
    for (int i = idx; i < nchunks; i += nt) hs4[i] = v;
}

// seed ring slot 0 with h_0 + 1.5 (generation 0 => positive sign)
__global__ void lstm_init0(const float* __restrict__ init_h,
                           short* __restrict__ hs, int R) {
    int idx = blockIdx.x * blockDim.x + threadIdx.x;
    int nt  = gridDim.x * blockDim.x;
    for (int e = idx; e < B_ * H_; e += nt) {
        int row = e >> 9, col = e & 511;
        int g = row >> 3, r8 = row & 7;
        hs[(size_t)g * R * 4096 + (size_t)r8 * 512 + col] = f2bf(init_h[e] + BIAS);
    }
}

__global__ void __launch_bounds__(256, 1) lstm_main(
    const float* __restrict__ obses, const float* __restrict__ init_c,
    const float* __restrict__ Wi,    const float* __restrict__ Wh,
    const float* __restrict__ bvec,  const float* __restrict__ Wv,
    const float* __restrict__ bv,    float* __restrict__ out,
    unsigned* ctl, short* hs, int R, int lg2R)
{
    const int bid = blockIdx.x;
    const int w   = threadIdx.x >> 6;
    const int l   = threadIdx.x & 63;
    const int n   = l & 15;
    const int kg  = l >> 4;
    const int Rm  = R - 1;
    const unsigned long long t_start = __builtin_amdgcn_s_memrealtime();
    bool tmo = false;

    if (bid < 128) {
        // ---------------- recurrence producer (transposed MFMA) ----------------
        __shared__ u64 lds_h[2][8 * 132];  // double-buffered: 8 rows x 128 u64
        const int g = bid & 7;
        const int k = bid >> 3;            // 0..15
        short* hsg = hs + (size_t)g * R * 4096;

        const int cw  = k * 32 + w * 8;            // wave's h-col base
        const int gc0 = (n & 3) * 512 + cw + (n >> 2);  // A-row n -> gate col (tile0)
        const int gc1 = gc0 + 4;                        // tile1 (+4 h-cols)

        // stationary weight A-frags + colsums
        bf16x8 whA0[16], whA1[16], wiA0[4], wiA1[4];
        float ws0 = 0.f, ws1 = 0.f;
#pragma unroll
        for (int ch = 0; ch < 16; ++ch) {
            bf16x8 v0, v1;
#pragma unroll
            for (int j = 0; j < 8; ++j) {
                const size_t kr = (size_t)(ch * 32 + kg * 8 + j) * G4_;
                short s0 = f2bf(Wh[kr + gc0]); v0[j] = s0; ws0 += bf2f(s0);
                short s1 = f2bf(Wh[kr + gc1]); v1[j] = s1; ws1 += bf2f(s1);
            }
            whA0[ch] = v0; whA1[ch] = v1;
        }
#pragma unroll
        for (int ch = 0; ch < 4; ++ch) {
            bf16x8 v0, v1;
#pragma unroll
            for (int j = 0; j < 8; ++j) {
                const size_t kr = (size_t)(ch * 32 + kg * 8 + j) * G4_;
                v0[j] = f2bf(Wi[kr + gc0]);
                v1[j] = f2bf(Wi[kr + gc1]);
            }
            wiA0[ch] = v0; wiA1[ch] = v1;
        }
        // full colsum over all 512 k-rows (reduce across kg)
        ws0 += __shfl_xor(ws0, 16); ws0 += __shfl_xor(ws0, 32);
        ws1 += __shfl_xor(ws1, 16); ws1 += __shfl_xor(ws1, 32);
        const float b0v = bvec[gc0], b1v = bvec[gc1];
        const float sP0 = b0v - BIAS * ws0, sM0 = b0v + BIAS * ws0;
        const float sP1 = b1v - BIAS * ws1, sM1 = b1v + BIAS * ws1;
        // per-acc-row seeds: row a = kg*4+r -> gather from lane a
        f32x4 sdP0, sdM0, sdP1, sdM1;
#pragma unroll
        for (int r = 0; r < 4; ++r) {
            sdP0[r] = __shfl(sP0, kg * 4 + r); sdM0[r] = __shfl(sM0, kg * 4 + r);
            sdP1[r] = __shfl(sP1, kg * 4 + r); sdM1[r] = __shfl(sM1, kg * 4 + r);
        }

        // c state: lane (kg, n<8) owns batch n, cols cw+kg (t0), cw+4+kg (t1)
        float cst0 = (n < 8) ? init_c[(size_t)(g * 8 + n) * H_ + cw + kg]     : 0.f;
        float cst1 = (n < 8) ? init_c[(size_t)(g * 8 + n) * H_ + cw + 4 + kg] : 0.f;
        float hl0 = 0.f, hl1 = 0.f;

        // obs double-buffer in registers
        f32x4 oraw[8];
        if (n < 8) {
            const float* src = obses + ((size_t)(g * 8 + n) * T_ + 0) * D_ + kg * 8;
#pragma unroll
            for (int ch = 0; ch < 4; ++ch) {
                oraw[2 * ch]     = *(const f32x4*)(src + ch * 32);
                oraw[2 * ch + 1] = *(const f32x4*)(src + ch * 32 + 4);
            }
        }

        // payload-quarter mapping
        const int prow = l >> 3;
        const int pcol = w * 32 + (l & 7);

        const int CHK  = R >> 2;
        const int CHKm = CHK - 1;

        for (int t = 0; t < T_ && !tmo; ++t) {
            // ---- back-pressure vs qs workers (rare) ----
            if ((t & CHKm) == 0) {
                const int need = t + CHK + 4 - R;
                if (need > 0) {
                    int spin = 0; bool ok;
                    do {
                        int p = 0x7fffffff;
                        if (l < 4)
                            p = 1 + l + 4 * (int)__hip_atomic_load(ctl + QD_IDX(g, l),
                                    __ATOMIC_RELAXED, __HIP_MEMORY_SCOPE_AGENT);
                        ok = (__all(p >= need) != 0);
                        if (!ok && ((++spin) & 63) == 0 &&
                            (__builtin_amdgcn_s_memrealtime() - t_start) > TLIM) { tmo = true; break; }
                    } while (!ok);
                    if (tmo) break;
                }
            }

            const bool  pos = (((t >> lg2R) & 1) == 0);
            const float bh1 = (((t + 1) >> lg2R) & 1) ? -BIAS : BIAS;

            // ---- x-projection from prefetched obs; prefetch next ----
            bf16x8 obsF[4];
#pragma unroll
            for (int ch = 0; ch < 4; ++ch) {
                bf16x8 v;
                if (n < 8) {
#pragma unroll
                    for (int j = 0; j < 4; ++j) {
                        v[j]     = f2bf(oraw[2 * ch][j]);
                        v[4 + j] = f2bf(oraw[2 * ch + 1][j]);
                    }
                } else {
#pragma unroll
                    for (int j = 0; j < 8; ++j) v[j] = 0;
                }
                obsF[ch] = v;
            }
            if (t + 1 < T_ && n < 8) {
                const float* src = obses + ((size_t)(g * 8 + n) * T_ + (t + 1)) * D_ + kg * 8;
#pragma unroll
                for (int ch = 0; ch < 4; ++ch) {
                    oraw[2 * ch]     = *(const f32x4*)(src + ch * 32);
                    oraw[2 * ch + 1] = *(const f32x4*)(src + ch * 32 + 4);
                }
            }

            // transposed xproj: A = Wi frags, B = obs frags; seeds per acc-row
            f32x4 aE0 = pos ? sdP0 : sdM0;
            f32x4 aE1 = pos ? sdP1 : sdM1;
            f32x4 aO0 = {0.f, 0.f, 0.f, 0.f}, aO1 = {0.f, 0.f, 0.f, 0.f};
            aE0 = MFMA(wiA0[0], obsF[0], aE0, 0, 0, 0);
            aO0 = MFMA(wiA0[1], obsF[1], aO0, 0, 0, 0);
            aE0 = MFMA(wiA0[2], obsF[2], aE0, 0, 0, 0);
            aO0 = MFMA(wiA0[3], obsF[3], aO0, 0, 0, 0);
            aE1 = MFMA(wiA1[0], obsF[0], aE1, 0, 0, 0);
            aO1 = MFMA(wiA1[1], obsF[1], aO1, 0, 0, 0);
            aE1 = MFMA(wiA1[2], obsF[2], aE1, 0, 0, 0);
            aO1 = MFMA(wiA1[3], obsF[3], aO1, 0, 0, 0);

            // ---- parity-poll OWN quarter (detecting read IS the payload) ----
            {
                const u64* hp = (const u64*)(hsg + (size_t)(t & Rm) * 4096)
                                + prow * 128 + pcol;
                const u64 e64 = pos ? 0ull : SMASK;
                u64 q0v, q1v, q2v, q3v;
                int spin = 0;
                for (;;) {
                    q0v = __hip_atomic_load(hp,      __ATOMIC_RELAXED, __HIP_MEMORY_SCOPE_AGENT);
                    q1v = __hip_atomic_load(hp + 8,  __ATOMIC_RELAXED, __HIP_MEMORY_SCOPE_AGENT);
                    q2v = __hip_atomic_load(hp + 16, __ATOMIC_RELAXED, __HIP_MEMORY_SCOPE_AGENT);
                    q3v = __hip_atomic_load(hp + 24, __ATOMIC_RELAXED, __HIP_MEMORY_SCOPE_AGENT);
                    u64 bad = (q0v ^ e64) | (q1v ^ e64) | (q2v ^ e64) | (q3v ^ e64);
                    if (__all((int)((bad & SMASK) == 0ull))) break;
                    if (((++spin) & 255) == 0 &&
                        (__builtin_amdgcn_s_memrealtime() - t_start) > TLIM) { tmo = true; break; }
                }
                if (tmo) break;
                u64* dst = &lds_h[t & 1][prow * 132 + pcol];
                dst[0]  = q0v;
                dst[8]  = q1v;
                dst[16] = q2v;
                dst[24] = q3v;
            }
            __syncthreads();

            // ---- recurrent MFMAs: A = Wh frags, B = h frags from LDS ----
            const u64* lb = &lds_h[t & 1][n * 132 + kg * 2];
#pragma unroll
            for (int ch = 0; ch < 16; ++ch) {
                union { u64 q[2]; bf16x8 v; } u;
                if (n < 8) { u.q[0] = lb[ch * 8]; u.q[1] = lb[ch * 8 + 1]; }
                else       { u.q[0] = 0ull; u.q[1] = 0ull; }
                if (ch & 1) { aO0 = MFMA(whA0[ch], u.v, aO0, 0, 0, 0);
                              aO1 = MFMA(whA1[ch], u.v, aO1, 0, 0, 0); }
                else        { aE0 = MFMA(whA0[ch], u.v, aE0, 0, 0, 0);
                              aE1 = MFMA(whA1[ch], u.v, aE1, 0, 0, 0); }
            }

            // ---- gates in-lane (acc regs = i,f,g,o of one h-col) ----
            f32x4 x0 = aE0 + aO0, x1 = aE1 + aO1;
            float nc0 = sigm(x0[1]) * cst0 + sigm(x0[0]) * tanh_(x0[2]);
            float nh0 = sigm(x0[3]) * tanh_(nc0);
            float nc1 = sigm(x1[1]) * cst1 + sigm(x1[0]) * tanh_(x1[2]);
            float nh1 = sigm(x1[3]) * tanh_(nc1);
            cst0 = nc0; cst1 = nc1; hl0 = nh0; hl1 = nh1;

            // ---- pack row segment (cols cw..cw+7) and publish ----
            {
                const int slw = (t + 1) & Rm;
                unsigned v = (unsigned)(unsigned short)f2bf(nh0 + bh1) |
                             ((unsigned)(unsigned short)f2bf(nh1 + bh1) << 16);
                unsigned p  = (unsigned)__shfl_xor((int)v, 16);   // kg^1
                unsigned dwA = (v & 0xffffu) | (p << 16);         // c0: kg, kg^1
                unsigned dwB = (v >> 16) | (p & 0xffff0000u);     // c1: kg, kg^1
                unsigned qA = (unsigned)__shfl_xor((int)dwA, 32); // kg^2 pair
                unsigned qB = (unsigned)__shfl_xor((int)dwB, 32);
                u64 lo = (u64)dwA | ((u64)qA << 32);  // cols cw+0..3
                u64 hi = (u64)dwB | ((u64)qB << 32);  // cols cw+4..7
                if (kg == 0 && n < 8) {
                    u64* dst = (u64*)(hsg + (size_t)slw * 4096 + (size_t)n * 512 + cw);
                    __hip_atomic_store(dst,     lo, __ATOMIC_RELAXED, __HIP_MEMORY_SCOPE_AGENT);
                    __hip_atomic_store(dst + 1, hi, __ATOMIC_RELAXED, __HIP_MEMORY_SCOPE_AGENT);
                }
            }
            // fire-and-forget — parity in the data is the flag
        }

        // ---- final c, h (fp32 from registers) ----
        if (n < 8 && !tmo) {
            const size_t brow = (size_t)(g * 8 + n);
            out[brow * H_ + cw + kg]     = cst0;
            out[brow * H_ + cw + 4 + kg] = cst1;
            out[(size_t)B_ * H_ + brow * H_ + cw + kg]     = hl0;
            out[(size_t)B_ * H_ + brow * H_ + cw + 4 + kg] = hl1;
        }
    } else {
        // ---------------- qs worker (1 CU per group) ----------------
        const int g = bid - 128;
        short* hsg = hs + (size_t)g * R * 4096;

        bf16x8 wvF[2][16]; float wvsum[2] = {0.f, 0.f}; float bvv[2];
#pragma unroll
        for (int c = 0; c < 2; ++c) {
            const int a  = c * 16 + n;
            const bool va = (a < A_);
#pragma unroll
            for (int ch = 0; ch < 16; ++ch) {
                bf16x8 v;
#pragma unroll
                for (int j = 0; j < 8; ++j) {
                    short sbf = va ? f2bf(Wv[(size_t)(ch * 32 + kg * 8 + j) * A_ + a]) : (short)0;
                    v[j] = sbf; wvsum[c] += bf2f(sbf);
                }
                wvF[c][ch] = v;
            }
            bvv[c] = va ? bv[a] : 0.f;
        }
#pragma unroll
        for (int c = 0; c < 2; ++c) {
            wvsum[c] += __shfl_xor(wvsum[c], 16);
            wvsum[c] += __shfl_xor(wvsum[c], 32);
        }

        u64 hq[32];
        if (n >= 8) {
#pragma unroll
            for (int i = 0; i < 32; ++i) hq[i] = 0ull;
        }

        unsigned cnt = 0;
        for (int s = 1 + w; s <= T_ && !tmo; s += 4) {
            const float bh = ((s >> lg2R) & 1) ? -BIAS : BIAS;
            const u64 e64 = (bh > 0.f) ? 0ull : SMASK;
            {
                const u64* hp = (const u64*)(hsg + (size_t)(s & Rm) * 4096)
                                + n * 128 + kg * 2;
                int spin = 0; bool fresh = true;
                do {
                    if (n < 8) {
                        u64 bad = 0;
#pragma unroll
                        for (int ch = 0; ch < 16; ++ch) {
                            hq[2 * ch]     = __hip_atomic_load(hp + ch * 8,     __ATOMIC_RELAXED, __HIP_MEMORY_SCOPE_AGENT);
                            hq[2 * ch + 1] = __hip_atomic_load(hp + ch * 8 + 1, __ATOMIC_RELAXED, __HIP_MEMORY_SCOPE_AGENT);
                        }
#pragma unroll
                        for (int i = 0; i < 32; ++i) bad |= (hq[i] ^ e64);
                        fresh = ((bad & SMASK) == 0ull);
                    }
                    if (__all(fresh)) break;
                    __builtin_amdgcn_s_sleep(2);
                    if (((++spin) & 255) == 0 &&
                        (__builtin_amdgcn_s_memrealtime() - t_start) > TLIM) { tmo = true; break; }
                } while (true);
                if (tmo) break;
            }

            // payload in regs -> progress immediately
            ++cnt;
            asm volatile("" ::: "memory");
            if (l == 0)
                __hip_atomic_store(ctl + QD_IDX(g, w), cnt,
                                   __ATOMIC_RELAXED, __HIP_MEMORY_SCOPE_AGENT);

            const float q0s = bvv[0] - bh * wvsum[0];
            const float q1s = bvv[1] - bh * wvsum[1];
            f32x4 q0 = {q0s, q0s, q0s, q0s};
            f32x4 q1 = {q1s, q1s, q1s, q1s};
#pragma unroll
            for (int ch = 0; ch < 16; ++ch) {
                union { u64 q[2]; bf16x8 v; } u;
                u.q[0] = hq[2 * ch]; u.q[1] = hq[2 * ch + 1];
                q0 = MFMA(u.v, wvF[0][ch], q0, 0, 0, 0);
                q1 = MFMA(u.v, wvF[1][ch], q1, 0, 0, 0);
            }

            const int tau = s - 1;
#pragma unroll
            for (int c = 0; c < 2; ++c) {
                const int a = c * 16 + n;
                if (kg < 2 && a < A_) {
                    const f32x4 q = c ? q1 : q0;
#pragma unroll
                    for (int r = 0; r < 4; ++r)
                        out[QOFF + ((size_t)(g * 8 + kg * 4 + r) * T_ + tau) * A_ + a] = q[r];
                }
            }
        }
    }
}

extern "C" void kernel_launch(void* const* d_in, const int* in_sizes, int n_in,
                              void* d_out, int out_size, void* d_ws, size_t ws_size,
                              hipStream_t stream) {
    const float* obses  = (const float*)d_in[0];
    const float* init_c = (const float*)d_in[1];
    const float* init_h = (const float*)d_in[2];
    const float* Wi     = (const float*)d_in[3];
    const float* Wh     = (const float*)d_in[4];
    const float* b      = (const float*)d_in[5];
    const float* Wv     = (const float*)d_in[6];
    const float* bv     = (const float*)d_in[7];
    float* out = (float*)d_out;

    unsigned* ctl = (unsigned*)d_ws;
    short*    hs  = (short*)((char*)d_ws + HS_OFF);

    int R = 32;
    while (R > 8 && (size_t)HS_OFF + 8ull * R * 8192ull > ws_size) R >>= 1;
    int lg2R = 31 - __builtin_clz((unsigned)R);

    int nchunks = R * 4096;  // 8 groups * R slots * 8192 B / 16 B

    hipLaunchKernelGGL(lstm_fill,  dim3(256), dim3(256), 0, stream, ctl, (uint4*)hs, nchunks);
    hipLaunchKernelGGL(lstm_init0, dim3(64),  dim3(256), 0, stream, init_h, hs, R);
    hipLaunchKernelGGL(lstm_main,  dim3(136), dim3(256), 0, stream,
                       obses, init_c, Wi, Wh, b, Wv, bv, out, ctl, hs, R, lg2R);
}